// Round 2
// baseline (1299.059 us; speedup 1.0000x reference)
//
#include <hip/hip_runtime.h>
#include <hip/hip_bf16.h>
#include <cstdint>

// Problem constants
// B=16, H=W=64, C=512, NH=16, WS=8, SS=4, P=4, HID=2048, N=64, HD=32
// Bw = 1024 windows, tokens = 65536

typedef __attribute__((ext_vector_type(8))) short short8;
typedef __attribute__((ext_vector_type(4))) float f32x4;
typedef unsigned short u16;

__device__ __forceinline__ u16 f2bf(float f) {
  __hip_bfloat16 h = __float2bfloat16(f);
  return *reinterpret_cast<u16*>(&h);
}

__device__ __forceinline__ void gld_lds16(const u16* g, u16* l) {
  __builtin_amdgcn_global_load_lds(
      (const __attribute__((address_space(1))) void*)g,
      (__attribute__((address_space(3))) void*)l, 16, 0, 0);
}

// ---------------------------------------------------------------------------
// Weight convert + transpose: W [K,N] fp32 -> Wt [N,K] bf16
// ---------------------------------------------------------------------------
__global__ void wt_convert(const float* __restrict__ W, u16* __restrict__ Wt,
                           int K, int N) {
  __shared__ float tile[32][33];
  const int n0 = blockIdx.x * 32, k0 = blockIdx.y * 32;
  const int tx = threadIdx.x & 31, ty = threadIdx.x >> 5;  // 32 x 8
#pragma unroll
  for (int r = ty; r < 32; r += 8)
    tile[r][tx] = W[(size_t)(k0 + r) * N + n0 + tx];
  __syncthreads();
#pragma unroll
  for (int r = ty; r < 32; r += 8)
    Wt[(size_t)(n0 + r) * K + k0 + tx] = f2bf(tile[tx][r]);
}

// ---------------------------------------------------------------------------
// A_phi precompute: [NH=16][n=64][m=64] fp32
// ---------------------------------------------------------------------------
__global__ void aphi_kernel(const float* __restrict__ a_p,
                            const float* __restrict__ b_p,
                            float* __restrict__ aphi) {
  const int idx = blockIdx.x * 256 + threadIdx.x;  // 65536 total
  const int h = idx >> 12, n = (idx >> 6) & 63, m = idx & 63;
  const float ang = (float)((n & 7) - (m & 7)) * 0.09817477042468103f;  // 2pi/64
  float v = a_p[h];
#pragma unroll
  for (int p = 0; p < 4; ++p) {
    float s, c;
    __sincosf((float)(p + 1) * ang, &s, &c);
    v += (c * a_p[(p + 1) * 16 + h] + s * b_p[p * 16 + h]) * 0.25f;
  }
  aphi[idx] = v;
}

// ---------------------------------------------------------------------------
// LN1 + roll(-4,-4) + window partition -> xw bf16 [65536,512], dw fp32 [65536]
// one wave per output row
// ---------------------------------------------------------------------------
__global__ __launch_bounds__(64) void ln1_win(
    const float* __restrict__ x, const float* __restrict__ D,
    const float* __restrict__ gamma, const float* __restrict__ beta,
    u16* __restrict__ xw, float* __restrict__ dwout) {
  const int r = blockIdx.x;
  const int lane = threadIdx.x;
  const int w = r >> 6, n = r & 63;
  const int bb = w >> 6, nw = w & 63;
  const int wh = nw >> 3, ww = nw & 7;
  const int i = n >> 3, j = n & 7;
  const int sh = (wh * 8 + i + 4) & 63;
  const int sw = (ww * 8 + j + 4) & 63;
  const size_t src = ((size_t)bb * 4096 + sh * 64 + sw) * 512;
  float4 v0 = *(const float4*)(x + src + lane * 8);
  float4 v1 = *(const float4*)(x + src + lane * 8 + 4);
  float vv[8] = {v0.x, v0.y, v0.z, v0.w, v1.x, v1.y, v1.z, v1.w};
  float s = 0.f, s2 = 0.f;
#pragma unroll
  for (int e = 0; e < 8; ++e) { s += vv[e]; s2 += vv[e] * vv[e]; }
#pragma unroll
  for (int off = 32; off > 0; off >>= 1) {
    s += __shfl_xor(s, off);
    s2 += __shfl_xor(s2, off);
  }
  const float mean = s * (1.0f / 512.0f);
  const float var = s2 * (1.0f / 512.0f) - mean * mean;
  const float rstd = rsqrtf(var + 1e-5f);
  const int c0 = lane * 8;
  u16 ob[8];
#pragma unroll
  for (int e = 0; e < 8; ++e)
    ob[e] = f2bf((vv[e] - mean) * rstd * gamma[c0 + e] + beta[c0 + e]);
  *(short8*)(xw + (size_t)r * 512 + c0) = *(short8*)ob;
  if (lane == 0) dwout[r] = D[(size_t)bb * 4096 + sh * 64 + sw];
}

// ---------------------------------------------------------------------------
// LN2 (token order): x2 fp32 -> h2 bf16
// ---------------------------------------------------------------------------
__global__ __launch_bounds__(64) void ln2_kernel(
    const float* __restrict__ xin, const float* __restrict__ gamma,
    const float* __restrict__ beta, u16* __restrict__ h2) {
  const int r = blockIdx.x;
  const int lane = threadIdx.x;
  const size_t src = (size_t)r * 512;
  float4 v0 = *(const float4*)(xin + src + lane * 8);
  float4 v1 = *(const float4*)(xin + src + lane * 8 + 4);
  float vv[8] = {v0.x, v0.y, v0.z, v0.w, v1.x, v1.y, v1.z, v1.w};
  float s = 0.f, s2 = 0.f;
#pragma unroll
  for (int e = 0; e < 8; ++e) { s += vv[e]; s2 += vv[e] * vv[e]; }
#pragma unroll
  for (int off = 32; off > 0; off >>= 1) {
    s += __shfl_xor(s, off);
    s2 += __shfl_xor(s2, off);
  }
  const float mean = s * (1.0f / 512.0f);
  const float var = s2 * (1.0f / 512.0f) - mean * mean;
  const float rstd = rsqrtf(var + 1e-5f);
  const int c0 = lane * 8;
  u16 ob[8];
#pragma unroll
  for (int e = 0; e < 8; ++e)
    ob[e] = f2bf((vv[e] - mean) * rstd * gamma[c0 + e] + beta[c0 + e]);
  *(short8*)(h2 + src + c0) = *(short8*)ob;
}

// ---------------------------------------------------------------------------
// bf16 GEMM, C[M,N] = A[M,K] * Bt[N,K]^T (+bias, +epilogue)
// 256x256 tile, BK=64, 512 threads = 8 waves (2M x 4N), 16x16x32 mfma.
// 8-phase template (T2+T3+T4+T5): per K-tile 4 phases; each phase stages one
// 16KB piece {Ak0,Bk0,Ak1,Bk1} of tile t+1 (2 x global_load_lds w16), reads
// its register subtile (plain ds_read_b128, compiler-visible deps), then
// s_barrier + lgkmcnt(0) + sched_barrier(0) + setprio(1){16 MFMA}setprio(0).
// Counted s_waitcnt vmcnt(6) ONLY at P0/P2 (k-half boundaries): the needed
// k-half is landed, 3 pieces (6 loads) stay in flight across barriers.
// LDS XOR swizzle chunk^((row>>1)&3) on 64B rows (2-way banks = free); the
// global SOURCE is pre-swizzled, LDS dest linear (global_load_lds rule).
// 1D grid + XCD swizzle: lid&7 stripes M across XCDs for A-panel L2 locality.
// EPI: 0 = bias->bf16; 1 = bias+gelu->bf16;
//      2 = bias + unwindow/unroll + residual(x) -> fp32 d_out;
//      3 = bias + accumulate into fp32 d_out (token order)
// ---------------------------------------------------------------------------
#define MFMA_BF16 __builtin_amdgcn_mfma_f32_16x16x32_bf16
#define SBAR __builtin_amdgcn_s_barrier()
#define SCHED0 __builtin_amdgcn_sched_barrier(0)
#define WAIT_LGKM0 asm volatile("s_waitcnt lgkmcnt(0)" ::: "memory")

template <int EPI, int GX>
__global__ __launch_bounds__(512, 2) void gemm_bt(
    const u16* __restrict__ A, const u16* __restrict__ Bt,
    const float* __restrict__ bias, u16* __restrict__ outb,
    float* __restrict__ outf, const float* __restrict__ addsrc,
    int M, int N, int K) {
  __shared__ __align__(16) u16 sA[2][16384];  // [buf][khalf(8192) | 256r x 32]
  __shared__ __align__(16) u16 sB[2][16384];
  const int t = threadIdx.x;
  const int lid = blockIdx.x;
  const int xcd = lid & 7;
  const int tt = lid >> 3;
  const int bx = tt % GX;
  const int by = (tt / GX) * 8 + xcd;
  const int m0 = by * 256, n0 = bx * 256;
  const int lane = t & 63, wave = t >> 6;
  const int wm = wave >> 2, wn = wave & 3;  // 2 x 4 wave grid
  const int l15 = lane & 15, quad = lane >> 4;

  f32x4 acc[8][4];
#pragma unroll
  for (int i = 0; i < 8; ++i)
#pragma unroll
    for (int j = 0; j < 4; ++j) acc[i][j] = (f32x4){0.f, 0.f, 0.f, 0.f};

  // staging map: piece = 16KB = 256 rows x 4 chunks(16B). thread t, load l:
  // slot = l*512+t -> row = slot>>2, phys chunk = slot&3,
  // logical chunk = phys ^ ((row>>1)&3)  (bank swizzle folded to global src)
  const int sr0 = t >> 2, sp0 = t & 3;
  const int sr1 = (t + 512) >> 2, sp1 = (t + 512) & 3;
  const int sc0 = sp0 ^ ((sr0 >> 1) & 3);
  const int sc1 = sp1 ^ ((sr1 >> 1) & 3);
  const int od0 = t * 8, od1 = (t + 512) * 8;  // u16 offsets within piece
  const u16* AgL0 = A + (size_t)(m0 + sr0) * K + sc0 * 8;
  const u16* AgL1 = A + (size_t)(m0 + sr1) * K + sc1 * 8;
  const u16* BgL0 = Bt + (size_t)(n0 + sr0) * K + sc0 * 8;
  const u16* BgL1 = Bt + (size_t)(n0 + sr1) * K + sc1 * 8;

#define STAGE_A(nb_, kh_, kt_)                                        \
  do {                                                                \
    gld_lds16(AgL0 + (kt_) * 64 + (kh_) * 32,                         \
              &sA[nb_][(kh_) * 8192 + od0]);                          \
    gld_lds16(AgL1 + (kt_) * 64 + (kh_) * 32,                         \
              &sA[nb_][(kh_) * 8192 + od1]);                          \
  } while (0)
#define STAGE_B(nb_, kh_, kt_)                                        \
  do {                                                                \
    gld_lds16(BgL0 + (kt_) * 64 + (kh_) * 32,                         \
              &sB[nb_][(kh_) * 8192 + od0]);                          \
    gld_lds16(BgL1 + (kt_) * 64 + (kh_) * 32,                         \
              &sB[nb_][(kh_) * 8192 + od1]);                          \
  } while (0)

  const int NT = K >> 6;  // K-tiles of 64

  // read-side constants (u16 offsets): row*32 + physchunk*8
  const int pch8 = (quad ^ ((l15 >> 1) & 3)) * 8;
  const int aro = (wm * 128 + l15) * 32 + pch8;  // + i*512 + kh*8192
  const int bro = (wn * 64 + l15) * 32 + pch8;   // + j*512 + kh*8192

  // Prologue: stage tile 0 (FIFO order = steady-state order: Ak0,Bk0,Ak1,Bk1)
  STAGE_A(0, 0, 0);
  STAGE_B(0, 0, 0);
  STAGE_A(0, 1, 0);
  STAGE_B(0, 1, 0);

  for (int kt = 0; kt < NT; ++kt) {
    const int b = kt & 1, nb = b ^ 1;
    const bool pf = (kt + 1 < NT);
    short8 a0[8], bb0, bb1;
    // ---- P0: k-half 0, j=0,1. Needs Ak0,Bk0 of tile kt landed.
    if (pf) {
      STAGE_A(nb, 0, kt + 1);
      asm volatile("s_waitcnt vmcnt(6)" ::: "memory");
    } else {
      asm volatile("s_waitcnt vmcnt(4)" ::: "memory");
    }
    SBAR;
#pragma unroll
    for (int i = 0; i < 8; ++i) a0[i] = *(const short8*)&sA[b][aro + i * 512];
    bb0 = *(const short8*)&sB[b][bro];
    bb1 = *(const short8*)&sB[b][bro + 512];
    WAIT_LGKM0;
    SCHED0;
    __builtin_amdgcn_s_setprio(1);
#pragma unroll
    for (int i = 0; i < 8; ++i) acc[i][0] = MFMA_BF16(a0[i], bb0, acc[i][0], 0, 0, 0);
#pragma unroll
    for (int i = 0; i < 8; ++i) acc[i][1] = MFMA_BF16(a0[i], bb1, acc[i][1], 0, 0, 0);
    __builtin_amdgcn_s_setprio(0);
    SCHED0;
    SBAR;
    // ---- P1: k-half 0, j=2,3 (A regs reused)
    if (pf) STAGE_B(nb, 0, kt + 1);
    bb0 = *(const short8*)&sB[b][bro + 1024];
    bb1 = *(const short8*)&sB[b][bro + 1536];
    SBAR;
    WAIT_LGKM0;
    SCHED0;
    __builtin_amdgcn_s_setprio(1);
#pragma unroll
    for (int i = 0; i < 8; ++i) acc[i][2] = MFMA_BF16(a0[i], bb0, acc[i][2], 0, 0, 0);
#pragma unroll
    for (int i = 0; i < 8; ++i) acc[i][3] = MFMA_BF16(a0[i], bb1, acc[i][3], 0, 0, 0);
    __builtin_amdgcn_s_setprio(0);
    SCHED0;
    SBAR;
    // ---- P2: k-half 1, j=0,1. Needs Ak1,Bk1 of tile kt landed.
    if (pf) {
      STAGE_A(nb, 1, kt + 1);
      asm volatile("s_waitcnt vmcnt(6)" ::: "memory");
    } else {
      asm volatile("s_waitcnt vmcnt(0)" ::: "memory");
    }
    SBAR;
#pragma unroll
    for (int i = 0; i < 8; ++i)
      a0[i] = *(const short8*)&sA[b][8192 + aro + i * 512];
    bb0 = *(const short8*)&sB[b][8192 + bro];
    bb1 = *(const short8*)&sB[b][8192 + bro + 512];
    WAIT_LGKM0;
    SCHED0;
    __builtin_amdgcn_s_setprio(1);
#pragma unroll
    for (int i = 0; i < 8; ++i) acc[i][0] = MFMA_BF16(a0[i], bb0, acc[i][0], 0, 0, 0);
#pragma unroll
    for (int i = 0; i < 8; ++i) acc[i][1] = MFMA_BF16(a0[i], bb1, acc[i][1], 0, 0, 0);
    __builtin_amdgcn_s_setprio(0);
    SCHED0;
    SBAR;
    // ---- P3: k-half 1, j=2,3
    if (pf) STAGE_B(nb, 1, kt + 1);
    bb0 = *(const short8*)&sB[b][8192 + bro + 1024];
    bb1 = *(const short8*)&sB[b][8192 + bro + 1536];
    SBAR;
    WAIT_LGKM0;
    SCHED0;
    __builtin_amdgcn_s_setprio(1);
#pragma unroll
    for (int i = 0; i < 8; ++i) acc[i][2] = MFMA_BF16(a0[i], bb0, acc[i][2], 0, 0, 0);
#pragma unroll
    for (int i = 0; i < 8; ++i) acc[i][3] = MFMA_BF16(a0[i], bb1, acc[i][3], 0, 0, 0);
    __builtin_amdgcn_s_setprio(0);
    SCHED0;
    SBAR;
  }

#pragma unroll
  for (int i = 0; i < 8; ++i) {
    const int gr0 = m0 + wm * 128 + i * 16 + quad * 4;
#pragma unroll
    for (int j = 0; j < 4; ++j) {
      const int gc = n0 + wn * 64 + j * 16 + l15;
      const float bv = bias[gc];
      f32x4 a = acc[i][j];
#pragma unroll
      for (int r = 0; r < 4; ++r) {
        const int gr = gr0 + r;
        float val = a[r] + bv;
        if (EPI == 0) {
          outb[(size_t)gr * N + gc] = f2bf(val);
        } else if (EPI == 1) {
          val = 0.5f * val * (1.0f + erff(val * 0.7071067811865475f));
          outb[(size_t)gr * N + gc] = f2bf(val);
        } else if (EPI == 2) {
          const int w = gr >> 6, n = gr & 63;
          const int bb = w >> 6, nw = w & 63;
          const int wh = nw >> 3, ww = nw & 7;
          const int ii = n >> 3, jj = n & 7;
          const int th = (wh * 8 + ii + 4) & 63;
          const int tw = (ww * 8 + jj + 4) & 63;
          const size_t tok = (size_t)bb * 4096 + th * 64 + tw;
          outf[tok * 512 + gc] = addsrc[tok * 512 + gc] + val;
        } else {
          outf[(size_t)gr * N + gc] += val;
        }
      }
    }
  }
}

// ---------------------------------------------------------------------------
// Fused windowed attention, one wave per (window, head).
// S = QK^T*scale + A_phi + A_r(trig recurrence) + shift-mask; in-register
// softmax (16-lane shuffles); P -> LDS -> A-frag; O = P V via mfma.
// ---------------------------------------------------------------------------
__device__ __forceinline__ int bandf(int p) {
  return p < 56 ? 0 : (p < 60 ? 1 : 2);
}

__global__ void attn_kernel(const u16* __restrict__ qkv,
                            const float* __restrict__ dw,
                            const float* __restrict__ aphi,
                            const float* __restrict__ a_r,
                            const float* __restrict__ b_r,
                            u16* __restrict__ outp) {
  __shared__ __align__(16) u16 sVt[32 * 72];
  __shared__ __align__(16) u16 sP[64 * 72];
  __shared__ float sdw[64];
  const int bid = blockIdx.x;
  const int w = bid >> 4, h = bid & 15;
  const int lane = threadIdx.x;
  const int l15 = lane & 15, quad = lane >> 4;
  const int nw = w & 63, wh = nw >> 3, wwc = nw & 7;

  const float ar0 = a_r[h];
  float arc[4], brc[4];
#pragma unroll
  for (int p = 0; p < 4; ++p) {
    arc[p] = a_r[(p + 1) * 16 + h] * 0.25f;
    brc[p] = b_r[p * 16 + h] * 0.25f;
  }

  sdw[lane] = dw[w * 64 + lane];
  {
    const u16* vrow = qkv + (size_t)(w * 64 + lane) * 1536 + 1024 + h * 32;
    u16 vt[32];
#pragma unroll
    for (int c = 0; c < 4; ++c)
      *(short8*)&vt[c * 8] = *(const short8*)(vrow + c * 8);
#pragma unroll
    for (int d = 0; d < 32; ++d) sVt[d * 72 + lane] = vt[d];
  }
  __syncthreads();

  short8 qf[4], kf[4];
#pragma unroll
  for (int tq = 0; tq < 4; ++tq) {
    qf[tq] = *(const short8*)(qkv + (size_t)(w * 64 + tq * 16 + l15) * 1536 +
                              h * 32 + quad * 8);
    kf[tq] = *(const short8*)(qkv + (size_t)(w * 64 + tq * 16 + l15) * 1536 +
                              512 + h * 32 + quad * 8);
  }

  float dn[16];
  int rq[16];
#pragma unroll
  for (int tm = 0; tm < 4; ++tm)
#pragma unroll
    for (int r = 0; r < 4; ++r) {
      const int n = tm * 16 + quad * 4 + r;
      dn[tm * 4 + r] = sdw[n];
      rq[tm * 4 + r] = bandf(wh * 8 + (n >> 3)) * 4 + bandf(wwc * 8 + (n & 7));
    }
  float dmv[4];
  int rk[4];
#pragma unroll
  for (int tn = 0; tn < 4; ++tn) {
    const int m = tn * 16 + l15;
    dmv[tn] = sdw[m];
    rk[tn] = bandf(wh * 8 + (m >> 3)) * 4 + bandf(wwc * 8 + (m & 7));
  }

  f32x4 S[4][4];
  const float SCALE = 0.17677669529663687f;  // 32^-0.5
#pragma unroll
  for (int tm = 0; tm < 4; ++tm)
#pragma unroll
    for (int tn = 0; tn < 4; ++tn) {
      f32x4 s = __builtin_amdgcn_mfma_f32_16x16x32_bf16(
          qf[tm], kf[tn], (f32x4){0.f, 0.f, 0.f, 0.f}, 0, 0, 0);
      const int m = tn * 16 + l15;
#pragma unroll
      for (int r = 0; r < 4; ++r) {
        const int n = tm * 16 + quad * 4 + r;
        const float rad = dmv[tn] - dn[tm * 4 + r];
        float s1, c1;
        __sincosf(3.14159265358979323846f * rad, &s1, &c1);
        const float c2 = c1 * c1 - s1 * s1, t2 = 2.f * s1 * c1;
        const float c3 = c2 * c1 - t2 * s1, t3 = t2 * c1 + c2 * s1;
        const float c4 = c2 * c2 - t2 * t2, t4 = 2.f * t2 * c2;
        const float arv = ar0 + c1 * arc[0] + s1 * brc[0] + c2 * arc[1] +
                          t2 * brc[1] + c3 * arc[2] + t3 * brc[2] +
                          c4 * arc[3] + t4 * brc[3];
        float val = s[r] * SCALE + aphi[h * 4096 + n * 64 + m] + arv;
        if (rq[tm * 4 + r] != rk[tn]) val -= 100.f;
        S[tm][tn][r] = val;
      }
    }

#pragma unroll
  for (int tm = 0; tm < 4; ++tm)
#pragma unroll
    for (int r = 0; r < 4; ++r) {
      float mx = fmaxf(fmaxf(S[tm][0][r], S[tm][1][r]),
                       fmaxf(S[tm][2][r], S[tm][3][r]));
#pragma unroll
      for (int off = 1; off < 16; off <<= 1) mx = fmaxf(mx, __shfl_xor(mx, off));
      float sm = 0.f;
#pragma unroll
      for (int tn = 0; tn < 4; ++tn) {
        const float e = __expf(S[tm][tn][r] - mx);
        S[tm][tn][r] = e;
        sm += e;
      }
#pragma unroll
      for (int off = 1; off < 16; off <<= 1) sm += __shfl_xor(sm, off);
      const float inv = 1.0f / sm;
      const int n = tm * 16 + quad * 4 + r;
#pragma unroll
      for (int tn = 0; tn < 4; ++tn)
        sP[n * 72 + tn * 16 + l15] = f2bf(S[tm][tn][r] * inv);
    }
  __syncthreads();

  short8 vf[2][2];
#pragma unroll
  for (int ks = 0; ks < 2; ++ks)
#pragma unroll
    for (int td = 0; td < 2; ++td)
      vf[ks][td] =
          *(const short8*)&sVt[(td * 16 + l15) * 72 + ks * 32 + quad * 8];
  f32x4 O[4][2];
#pragma unroll
  for (int tm = 0; tm < 4; ++tm)
#pragma unroll
    for (int td = 0; td < 2; ++td) O[tm][td] = (f32x4){0.f, 0.f, 0.f, 0.f};
#pragma unroll
  for (int tm = 0; tm < 4; ++tm)
#pragma unroll
    for (int ks = 0; ks < 2; ++ks) {
      const short8 pf =
          *(const short8*)&sP[(tm * 16 + l15) * 72 + ks * 32 + quad * 8];
#pragma unroll
      for (int td = 0; td < 2; ++td)
        O[tm][td] =
            __builtin_amdgcn_mfma_f32_16x16x32_bf16(pf, vf[ks][td], O[tm][td], 0, 0, 0);
    }

#pragma unroll
  for (int tm = 0; tm < 4; ++tm)
#pragma unroll
    for (int td = 0; td < 2; ++td)
#pragma unroll
      for (int r = 0; r < 4; ++r) {
        const int n = tm * 16 + quad * 4 + r;
        const int d = td * 16 + l15;
        outp[(size_t)(w * 64 + n) * 512 + h * 32 + d] = f2bf(O[tm][td][r]);
      }
}

// ---------------------------------------------------------------------------
// Host
// ---------------------------------------------------------------------------
extern "C" void kernel_launch(void* const* d_in, const int* in_sizes, int n_in,
                              void* d_out, int out_size, void* d_ws,
                              size_t ws_size, hipStream_t stream) {
  const float* x = (const float*)d_in[0];
  const float* D = (const float*)d_in[1];
  const float* gamma1 = (const float*)d_in[2];
  const float* beta1 = (const float*)d_in[3];
  const float* Wqkv = (const float*)d_in[4];
  const float* bqkv = (const float*)d_in[5];
  const float* Wproj = (const float*)d_in[6];
  const float* bproj = (const float*)d_in[7];
  const float* a_p = (const float*)d_in[8];
  const float* b_p = (const float*)d_in[9];
  const float* a_r = (const float*)d_in[10];
  const float* b_r = (const float*)d_in[11];
  const float* gamma2 = (const float*)d_in[12];
  const float* beta2 = (const float*)d_in[13];
  const float* W1 = (const float*)d_in[14];
  const float* b1 = (const float*)d_in[15];
  const float* W2 = (const float*)d_in[16];
  const float* b2 = (const float*)d_in[17];
  float* out = (float*)d_out;

  char* ws = (char*)d_ws;
  const size_t OFF_XW = 0;                    // 67,108,864   (xw, later h2)
  const size_t OFF_QKV = 67108864;            // 268,435,456  (qkv, later g)
  const size_t OFF_AO = 335544320;            // 67,108,864   (attn out)
  const size_t OFF_WQT = 402653184;           // 1,572,864
  const size_t OFF_WPT = 404226048;           // 524,288
  const size_t OFF_W1T = 404750336;           // 2,097,152
  const size_t OFF_W2T = 406847488;           // 2,097,152
  const size_t OFF_APHI = 408944640;          // 262,144
  const size_t OFF_DW = 409206784;            // 262,144
  const size_t TOTAL = 409468928;
  if (ws_size < TOTAL) return;

  u16* xw = (u16*)(ws + OFF_XW);
  u16* qkv = (u16*)(ws + OFF_QKV);
  u16* ao = (u16*)(ws + OFF_AO);
  u16* WqkvT = (u16*)(ws + OFF_WQT);
  u16* WprojT = (u16*)(ws + OFF_WPT);
  u16* W1T = (u16*)(ws + OFF_W1T);
  u16* W2T = (u16*)(ws + OFF_W2T);
  float* aphiW = (float*)(ws + OFF_APHI);
  float* dwW = (float*)(ws + OFF_DW);
  u16* h2 = xw;   // reuse
  u16* gbuf = qkv;  // reuse

  wt_convert<<<dim3(48, 16), 256, 0, stream>>>(Wqkv, WqkvT, 512, 1536);
  wt_convert<<<dim3(16, 16), 256, 0, stream>>>(Wproj, WprojT, 512, 512);
  wt_convert<<<dim3(64, 16), 256, 0, stream>>>(W1, W1T, 512, 2048);
  wt_convert<<<dim3(16, 64), 256, 0, stream>>>(W2, W2T, 2048, 512);
  aphi_kernel<<<256, 256, 0, stream>>>(a_p, b_p, aphiW);
  ln1_win<<<65536, 64, 0, stream>>>(x, D, gamma1, beta1, xw, dwW);

  // 256x256 tiles: grid = (N/256) * 256 M-tiles
  gemm_bt<0, 6><<<6 * 256, 512, 0, stream>>>(xw, WqkvT, bqkv, qkv, nullptr,
                                             nullptr, 65536, 1536, 512);
  attn_kernel<<<16384, 64, 0, stream>>>(qkv, dwW, aphiW, a_r, b_r, ao);
  gemm_bt<2, 2><<<2 * 256, 512, 0, stream>>>(ao, WprojT, bproj, nullptr, out,
                                             x, 65536, 512, 512);
  ln2_kernel<<<65536, 64, 0, stream>>>(out, gamma2, beta2, h2);
  gemm_bt<1, 8><<<8 * 256, 512, 0, stream>>>(h2, W1T, b1, gbuf, nullptr,
                                             nullptr, 65536, 2048, 512);
  gemm_bt<3, 2><<<2 * 256, 512, 0, stream>>>(gbuf, W2T, b2, nullptr, out,
                                             nullptr, 65536, 512, 2048);
}

// Round 3
// 1254.983 us; speedup vs baseline: 1.0351x; 1.0351x over previous
//
#include <hip/hip_runtime.h>
#include <hip/hip_bf16.h>
#include <cstdint>

// Problem constants
// B=16, H=W=64, C=512, NH=16, WS=8, SS=4, P=4, HID=2048, N=64, HD=32
// Bw = 1024 windows, tokens = 65536

typedef __attribute__((ext_vector_type(8))) short short8;
typedef __attribute__((ext_vector_type(4))) float f32x4;
typedef unsigned short u16;

__device__ __forceinline__ u16 f2bf(float f) {
  __hip_bfloat16 h = __float2bfloat16(f);
  return *reinterpret_cast<u16*>(&h);
}

__device__ __forceinline__ void gld_lds16(const u16* g, u16* l) {
  __builtin_amdgcn_global_load_lds(
      (const __attribute__((address_space(1))) void*)g,
      (__attribute__((address_space(3))) void*)l, 16, 0, 0);
}

// ---------------------------------------------------------------------------
// Weight convert + transpose: W [K,N] fp32 -> Wt [N,K] bf16
// ---------------------------------------------------------------------------
__global__ void wt_convert(const float* __restrict__ W, u16* __restrict__ Wt,
                           int K, int N) {
  __shared__ float tile[32][33];
  const int n0 = blockIdx.x * 32, k0 = blockIdx.y * 32;
  const int tx = threadIdx.x & 31, ty = threadIdx.x >> 5;  // 32 x 8
#pragma unroll
  for (int r = ty; r < 32; r += 8)
    tile[r][tx] = W[(size_t)(k0 + r) * N + n0 + tx];
  __syncthreads();
#pragma unroll
  for (int r = ty; r < 32; r += 8)
    Wt[(size_t)(n0 + r) * K + k0 + tx] = f2bf(tile[tx][r]);
}

// ---------------------------------------------------------------------------
// A_phi precompute: [NH=16][n=64][m=64] fp32
// ---------------------------------------------------------------------------
__global__ void aphi_kernel(const float* __restrict__ a_p,
                            const float* __restrict__ b_p,
                            float* __restrict__ aphi) {
  const int idx = blockIdx.x * 256 + threadIdx.x;  // 65536 total
  const int h = idx >> 12, n = (idx >> 6) & 63, m = idx & 63;
  const float ang = (float)((n & 7) - (m & 7)) * 0.09817477042468103f;  // 2pi/64
  float v = a_p[h];
#pragma unroll
  for (int p = 0; p < 4; ++p) {
    float s, c;
    __sincosf((float)(p + 1) * ang, &s, &c);
    v += (c * a_p[(p + 1) * 16 + h] + s * b_p[p * 16 + h]) * 0.25f;
  }
  aphi[idx] = v;
}

// ---------------------------------------------------------------------------
// LN1 + roll(-4,-4) + window partition -> xw bf16 [65536,512], dw fp32 [65536]
// one wave per output row
// ---------------------------------------------------------------------------
__global__ __launch_bounds__(64) void ln1_win(
    const float* __restrict__ x, const float* __restrict__ D,
    const float* __restrict__ gamma, const float* __restrict__ beta,
    u16* __restrict__ xw, float* __restrict__ dwout) {
  const int r = blockIdx.x;
  const int lane = threadIdx.x;
  const int w = r >> 6, n = r & 63;
  const int bb = w >> 6, nw = w & 63;
  const int wh = nw >> 3, ww = nw & 7;
  const int i = n >> 3, j = n & 7;
  const int sh = (wh * 8 + i + 4) & 63;
  const int sw = (ww * 8 + j + 4) & 63;
  const size_t src = ((size_t)bb * 4096 + sh * 64 + sw) * 512;
  float4 v0 = *(const float4*)(x + src + lane * 8);
  float4 v1 = *(const float4*)(x + src + lane * 8 + 4);
  float vv[8] = {v0.x, v0.y, v0.z, v0.w, v1.x, v1.y, v1.z, v1.w};
  float s = 0.f, s2 = 0.f;
#pragma unroll
  for (int e = 0; e < 8; ++e) { s += vv[e]; s2 += vv[e] * vv[e]; }
#pragma unroll
  for (int off = 32; off > 0; off >>= 1) {
    s += __shfl_xor(s, off);
    s2 += __shfl_xor(s2, off);
  }
  const float mean = s * (1.0f / 512.0f);
  const float var = s2 * (1.0f / 512.0f) - mean * mean;
  const float rstd = rsqrtf(var + 1e-5f);
  const int c0 = lane * 8;
  u16 ob[8];
#pragma unroll
  for (int e = 0; e < 8; ++e)
    ob[e] = f2bf((vv[e] - mean) * rstd * gamma[c0 + e] + beta[c0 + e]);
  *(short8*)(xw + (size_t)r * 512 + c0) = *(short8*)ob;
  if (lane == 0) dwout[r] = D[(size_t)bb * 4096 + sh * 64 + sw];
}

// ---------------------------------------------------------------------------
// LN2 (token order): x2 fp32 -> h2 bf16
// ---------------------------------------------------------------------------
__global__ __launch_bounds__(64) void ln2_kernel(
    const float* __restrict__ xin, const float* __restrict__ gamma,
    const float* __restrict__ beta, u16* __restrict__ h2) {
  const int r = blockIdx.x;
  const int lane = threadIdx.x;
  const size_t src = (size_t)r * 512;
  float4 v0 = *(const float4*)(xin + src + lane * 8);
  float4 v1 = *(const float4*)(xin + src + lane * 8 + 4);
  float vv[8] = {v0.x, v0.y, v0.z, v0.w, v1.x, v1.y, v1.z, v1.w};
  float s = 0.f, s2 = 0.f;
#pragma unroll
  for (int e = 0; e < 8; ++e) { s += vv[e]; s2 += vv[e] * vv[e]; }
#pragma unroll
  for (int off = 32; off > 0; off >>= 1) {
    s += __shfl_xor(s, off);
    s2 += __shfl_xor(s2, off);
  }
  const float mean = s * (1.0f / 512.0f);
  const float var = s2 * (1.0f / 512.0f) - mean * mean;
  const float rstd = rsqrtf(var + 1e-5f);
  const int c0 = lane * 8;
  u16 ob[8];
#pragma unroll
  for (int e = 0; e < 8; ++e)
    ob[e] = f2bf((vv[e] - mean) * rstd * gamma[c0 + e] + beta[c0 + e]);
  *(short8*)(h2 + src + c0) = *(short8*)ob;
}

// ---------------------------------------------------------------------------
// bf16 GEMM, C[M,N] = A[M,K] * Bt[N,K]^T (+bias, +epilogue)
// 256x256 tile, BK=64, 512 threads = 8 waves (2M x 4N), 16x16x32 mfma.
// 8-phase template, R3 fix: each 16KB staging piece is its OWN __shared__
// object and the K-loop is unrolled 2 tiles/iter so every piece pointer is a
// compile-time constant -> the compiler's waitcnt pass can disambiguate
// ds_read vs in-flight global_load_lds DMA and emits COUNTED vmcnt (not the
// conservative vmcnt(0) that nullified R1/R2's pipeline).
// Counted s_waitcnt vmcnt(6) at P0/P2 only; tail tile vmcnt(4)/vmcnt(0).
// LDS XOR swizzle chunk^((row>>1)&3) on 64B rows, pre-swizzled global src.
// 1D grid + XCD swizzle: lid&7 stripes M across XCDs for A-panel L2 locality.
// EPI: 0 = bias->bf16; 1 = bias+gelu->bf16;
//      2 = bias + unwindow/unroll + residual(x) -> fp32 d_out;
//      3 = bias + accumulate into fp32 d_out (token order)
// ---------------------------------------------------------------------------
#define MFMA_BF16 __builtin_amdgcn_mfma_f32_16x16x32_bf16
#define SBAR __builtin_amdgcn_s_barrier()
#define SCHED0 __builtin_amdgcn_sched_barrier(0)
#define WAIT_LGKM0 asm volatile("s_waitcnt lgkmcnt(0)" ::: "memory")

template <int W>
__device__ __forceinline__ void wait_vm() {
  if constexpr (W == 6)
    asm volatile("s_waitcnt vmcnt(6)" ::: "memory");
  else if constexpr (W == 4)
    asm volatile("s_waitcnt vmcnt(4)" ::: "memory");
  else
    asm volatile("s_waitcnt vmcnt(0)" ::: "memory");
}

// One K-tile = 4 phases. Reads pieces RA0/RA1/RB0/RB1 (tile kt, this buffer),
// stages pieces of tile kt+1 into SA0/SA1/SB0/SB1 (other buffer) if STAGE.
template <bool STAGE>
__device__ __forceinline__ void ktile(
    f32x4 (&acc)[8][4], const u16* RA0, const u16* RA1, const u16* RB0,
    const u16* RB1, u16* SA0, u16* SA1, u16* SB0, u16* SB1, const u16* AgL0,
    const u16* AgL1, const u16* BgL0, const u16* BgL1, int kn64, int od0,
    int od1, int aro, int bro) {
  short8 a0[8], bb0, bb1;
  // ---- P0: khalf0, j=0,1. Guard: A-k0,B-k0 of this tile landed.
  if (STAGE) {
    gld_lds16(AgL0 + kn64, &SA0[od0]);
    gld_lds16(AgL1 + kn64, &SA0[od1]);
    wait_vm<6>();
  } else {
    wait_vm<4>();
  }
  SBAR;
#pragma unroll
  for (int i = 0; i < 8; ++i) a0[i] = *(const short8*)&RA0[aro + i * 512];
  bb0 = *(const short8*)&RB0[bro];
  bb1 = *(const short8*)&RB0[bro + 512];
  WAIT_LGKM0;
  SCHED0;
  __builtin_amdgcn_s_setprio(1);
#pragma unroll
  for (int i = 0; i < 8; ++i) acc[i][0] = MFMA_BF16(a0[i], bb0, acc[i][0], 0, 0, 0);
#pragma unroll
  for (int i = 0; i < 8; ++i) acc[i][1] = MFMA_BF16(a0[i], bb1, acc[i][1], 0, 0, 0);
  __builtin_amdgcn_s_setprio(0);
  SCHED0;
  SBAR;
  // ---- P1: khalf0, j=2,3 (A regs reused)
  if (STAGE) {
    gld_lds16(BgL0 + kn64, &SB0[od0]);
    gld_lds16(BgL1 + kn64, &SB0[od1]);
  }
  bb0 = *(const short8*)&RB0[bro + 1024];
  bb1 = *(const short8*)&RB0[bro + 1536];
  SBAR;
  WAIT_LGKM0;
  SCHED0;
  __builtin_amdgcn_s_setprio(1);
#pragma unroll
  for (int i = 0; i < 8; ++i) acc[i][2] = MFMA_BF16(a0[i], bb0, acc[i][2], 0, 0, 0);
#pragma unroll
  for (int i = 0; i < 8; ++i) acc[i][3] = MFMA_BF16(a0[i], bb1, acc[i][3], 0, 0, 0);
  __builtin_amdgcn_s_setprio(0);
  SCHED0;
  SBAR;
  // ---- P2: khalf1, j=0,1. Guard: A-k1,B-k1 of this tile landed.
  if (STAGE) {
    gld_lds16(AgL0 + kn64 + 32, &SA1[od0]);
    gld_lds16(AgL1 + kn64 + 32, &SA1[od1]);
    wait_vm<6>();
  } else {
    wait_vm<0>();
  }
  SBAR;
#pragma unroll
  for (int i = 0; i < 8; ++i) a0[i] = *(const short8*)&RA1[aro + i * 512];
  bb0 = *(const short8*)&RB1[bro];
  bb1 = *(const short8*)&RB1[bro + 512];
  WAIT_LGKM0;
  SCHED0;
  __builtin_amdgcn_s_setprio(1);
#pragma unroll
  for (int i = 0; i < 8; ++i) acc[i][0] = MFMA_BF16(a0[i], bb0, acc[i][0], 0, 0, 0);
#pragma unroll
  for (int i = 0; i < 8; ++i) acc[i][1] = MFMA_BF16(a0[i], bb1, acc[i][1], 0, 0, 0);
  __builtin_amdgcn_s_setprio(0);
  SCHED0;
  SBAR;
  // ---- P3: khalf1, j=2,3
  if (STAGE) {
    gld_lds16(BgL0 + kn64 + 32, &SB1[od0]);
    gld_lds16(BgL1 + kn64 + 32, &SB1[od1]);
  }
  bb0 = *(const short8*)&RB1[bro + 1024];
  bb1 = *(const short8*)&RB1[bro + 1536];
  SBAR;
  WAIT_LGKM0;
  SCHED0;
  __builtin_amdgcn_s_setprio(1);
#pragma unroll
  for (int i = 0; i < 8; ++i) acc[i][2] = MFMA_BF16(a0[i], bb0, acc[i][2], 0, 0, 0);
#pragma unroll
  for (int i = 0; i < 8; ++i) acc[i][3] = MFMA_BF16(a0[i], bb1, acc[i][3], 0, 0, 0);
  __builtin_amdgcn_s_setprio(0);
  SCHED0;
  SBAR;
}

template <int EPI, int GX>
__global__ __launch_bounds__(512, 2) void gemm_bt(
    const u16* __restrict__ A, const u16* __restrict__ Bt,
    const float* __restrict__ bias, u16* __restrict__ outb,
    float* __restrict__ outf, const float* __restrict__ addsrc,
    int M, int N, int K) {
  // 8 separate 16KB pieces: {A,B} x {buf0,buf1} x {khalf0,khalf1}
  __shared__ __align__(16) u16 sA0h0[8192], sA0h1[8192];
  __shared__ __align__(16) u16 sA1h0[8192], sA1h1[8192];
  __shared__ __align__(16) u16 sB0h0[8192], sB0h1[8192];
  __shared__ __align__(16) u16 sB1h0[8192], sB1h1[8192];
  const int t = threadIdx.x;
  const int lid = blockIdx.x;
  const int xcd = lid & 7;
  const int tt = lid >> 3;
  const int bx = tt % GX;
  const int by = (tt / GX) * 8 + xcd;
  const int m0 = by * 256, n0 = bx * 256;
  const int lane = t & 63, wave = t >> 6;
  const int wm = wave >> 2, wn = wave & 3;  // 2 x 4 wave grid
  const int l15 = lane & 15, quad = lane >> 4;

  f32x4 acc[8][4];
#pragma unroll
  for (int i = 0; i < 8; ++i)
#pragma unroll
    for (int j = 0; j < 4; ++j) acc[i][j] = (f32x4){0.f, 0.f, 0.f, 0.f};

  // staging map: piece = 16KB = 256 rows x 4 chunks(16B). thread t, load l:
  // slot = l*512+t -> row = slot>>2, phys chunk = slot&3,
  // logical chunk = phys ^ ((row>>1)&3)  (bank swizzle folded to global src)
  const int sr0 = t >> 2, sp0 = t & 3;
  const int sr1 = (t + 512) >> 2, sp1 = (t + 512) & 3;
  const int sc0 = sp0 ^ ((sr0 >> 1) & 3);
  const int sc1 = sp1 ^ ((sr1 >> 1) & 3);
  const int od0 = t * 8, od1 = (t + 512) * 8;  // u16 offsets within piece
  const u16* AgL0 = A + (size_t)(m0 + sr0) * K + sc0 * 8;
  const u16* AgL1 = A + (size_t)(m0 + sr1) * K + sc1 * 8;
  const u16* BgL0 = Bt + (size_t)(n0 + sr0) * K + sc0 * 8;
  const u16* BgL1 = Bt + (size_t)(n0 + sr1) * K + sc1 * 8;

  const int NT = K >> 6;  // K-tiles of 64 (all K here: NT even, >= 8)

  // read-side constants (u16 offsets): row*32 + physchunk*8
  const int pch8 = (quad ^ ((l15 >> 1) & 3)) * 8;
  const int aro = (wm * 128 + l15) * 32 + pch8;  // + i*512
  const int bro = (wn * 64 + l15) * 32 + pch8;   // + j*512

  // Prologue: stage tile 0 into buf0, FIFO order A-k0, B-k0, A-k1, B-k1
  gld_lds16(AgL0, &sA0h0[od0]);
  gld_lds16(AgL1, &sA0h0[od1]);
  gld_lds16(BgL0, &sB0h0[od0]);
  gld_lds16(BgL1, &sB0h0[od1]);
  gld_lds16(AgL0 + 32, &sA0h1[od0]);
  gld_lds16(AgL1 + 32, &sA0h1[od1]);
  gld_lds16(BgL0 + 32, &sB0h1[od0]);
  gld_lds16(BgL1 + 32, &sB0h1[od1]);

  int kt = 0;
  for (; kt + 2 < NT; kt += 2) {
    ktile<true>(acc, sA0h0, sA0h1, sB0h0, sB0h1, sA1h0, sA1h1, sB1h0, sB1h1,
                AgL0, AgL1, BgL0, BgL1, (kt + 1) * 64, od0, od1, aro, bro);
    ktile<true>(acc, sA1h0, sA1h1, sB1h0, sB1h1, sA0h0, sA0h1, sB0h0, sB0h1,
                AgL0, AgL1, BgL0, BgL1, (kt + 2) * 64, od0, od1, aro, bro);
  }
  // last pair: tile NT-2 stages NT-1 into buf1; tile NT-1 drains (no stage)
  ktile<true>(acc, sA0h0, sA0h1, sB0h0, sB0h1, sA1h0, sA1h1, sB1h0, sB1h1,
              AgL0, AgL1, BgL0, BgL1, (kt + 1) * 64, od0, od1, aro, bro);
  ktile<false>(acc, sA1h0, sA1h1, sB1h0, sB1h1, sA0h0, sA0h1, sB0h0, sB0h1,
               AgL0, AgL1, BgL0, BgL1, 0, od0, od1, aro, bro);

#pragma unroll
  for (int i = 0; i < 8; ++i) {
    const int gr0 = m0 + wm * 128 + i * 16 + quad * 4;
#pragma unroll
    for (int j = 0; j < 4; ++j) {
      const int gc = n0 + wn * 64 + j * 16 + l15;
      const float bv = bias[gc];
      f32x4 a = acc[i][j];
#pragma unroll
      for (int r = 0; r < 4; ++r) {
        const int gr = gr0 + r;
        float val = a[r] + bv;
        if (EPI == 0) {
          outb[(size_t)gr * N + gc] = f2bf(val);
        } else if (EPI == 1) {
          val = 0.5f * val * (1.0f + erff(val * 0.7071067811865475f));
          outb[(size_t)gr * N + gc] = f2bf(val);
        } else if (EPI == 2) {
          const int w = gr >> 6, n = gr & 63;
          const int bb = w >> 6, nw = w & 63;
          const int wh = nw >> 3, ww = nw & 7;
          const int ii = n >> 3, jj = n & 7;
          const int th = (wh * 8 + ii + 4) & 63;
          const int tw = (ww * 8 + jj + 4) & 63;
          const size_t tok = (size_t)bb * 4096 + th * 64 + tw;
          outf[tok * 512 + gc] = addsrc[tok * 512 + gc] + val;
        } else {
          outf[(size_t)gr * N + gc] += val;
        }
      }
    }
  }
}

// ---------------------------------------------------------------------------
// Fused windowed attention, one wave per (window, head).
// S = QK^T*scale + A_phi + A_r(trig recurrence) + shift-mask; in-register
// softmax (16-lane shuffles); P -> LDS -> A-frag; O = P V via mfma.
// ---------------------------------------------------------------------------
__device__ __forceinline__ int bandf(int p) {
  return p < 56 ? 0 : (p < 60 ? 1 : 2);
}

__global__ void attn_kernel(const u16* __restrict__ qkv,
                            const float* __restrict__ dw,
                            const float* __restrict__ aphi,
                            const float* __restrict__ a_r,
                            const float* __restrict__ b_r,
                            u16* __restrict__ outp) {
  __shared__ __align__(16) u16 sVt[32 * 72];
  __shared__ __align__(16) u16 sP[64 * 72];
  __shared__ float sdw[64];
  const int bid = blockIdx.x;
  const int w = bid >> 4, h = bid & 15;
  const int lane = threadIdx.x;
  const int l15 = lane & 15, quad = lane >> 4;
  const int nw = w & 63, wh = nw >> 3, wwc = nw & 7;

  const float ar0 = a_r[h];
  float arc[4], brc[4];
#pragma unroll
  for (int p = 0; p < 4; ++p) {
    arc[p] = a_r[(p + 1) * 16 + h] * 0.25f;
    brc[p] = b_r[p * 16 + h] * 0.25f;
  }

  sdw[lane] = dw[w * 64 + lane];
  {
    const u16* vrow = qkv + (size_t)(w * 64 + lane) * 1536 + 1024 + h * 32;
    u16 vt[32];
#pragma unroll
    for (int c = 0; c < 4; ++c)
      *(short8*)&vt[c * 8] = *(const short8*)(vrow + c * 8);
#pragma unroll
    for (int d = 0; d < 32; ++d) sVt[d * 72 + lane] = vt[d];
  }
  __syncthreads();

  short8 qf[4], kf[4];
#pragma unroll
  for (int tq = 0; tq < 4; ++tq) {
    qf[tq] = *(const short8*)(qkv + (size_t)(w * 64 + tq * 16 + l15) * 1536 +
                              h * 32 + quad * 8);
    kf[tq] = *(const short8*)(qkv + (size_t)(w * 64 + tq * 16 + l15) * 1536 +
                              512 + h * 32 + quad * 8);
  }

  float dn[16];
  int rq[16];
#pragma unroll
  for (int tm = 0; tm < 4; ++tm)
#pragma unroll
    for (int r = 0; r < 4; ++r) {
      const int n = tm * 16 + quad * 4 + r;
      dn[tm * 4 + r] = sdw[n];
      rq[tm * 4 + r] = bandf(wh * 8 + (n >> 3)) * 4 + bandf(wwc * 8 + (n & 7));
    }
  float dmv[4];
  int rk[4];
#pragma unroll
  for (int tn = 0; tn < 4; ++tn) {
    const int m = tn * 16 + l15;
    dmv[tn] = sdw[m];
    rk[tn] = bandf(wh * 8 + (m >> 3)) * 4 + bandf(wwc * 8 + (m & 7));
  }

  f32x4 S[4][4];
  const float SCALE = 0.17677669529663687f;  // 32^-0.5
#pragma unroll
  for (int tm = 0; tm < 4; ++tm)
#pragma unroll
    for (int tn = 0; tn < 4; ++tn) {
      f32x4 s = __builtin_amdgcn_mfma_f32_16x16x32_bf16(
          qf[tm], kf[tn], (f32x4){0.f, 0.f, 0.f, 0.f}, 0, 0, 0);
      const int m = tn * 16 + l15;
#pragma unroll
      for (int r = 0; r < 4; ++r) {
        const int n = tm * 16 + quad * 4 + r;
        const float rad = dmv[tn] - dn[tm * 4 + r];
        float s1, c1;
        __sincosf(3.14159265358979323846f * rad, &s1, &c1);
        const float c2 = c1 * c1 - s1 * s1, t2 = 2.f * s1 * c1;
        const float c3 = c2 * c1 - t2 * s1, t3 = t2 * c1 + c2 * s1;
        const float c4 = c2 * c2 - t2 * t2, t4 = 2.f * t2 * c2;
        const float arv = ar0 + c1 * arc[0] + s1 * brc[0] + c2 * arc[1] +
                          t2 * brc[1] + c3 * arc[2] + t3 * brc[2] +
                          c4 * arc[3] + t4 * brc[3];
        float val = s[r] * SCALE + aphi[h * 4096 + n * 64 + m] + arv;
        if (rq[tm * 4 + r] != rk[tn]) val -= 100.f;
        S[tm][tn][r] = val;
      }
    }

#pragma unroll
  for (int tm = 0; tm < 4; ++tm)
#pragma unroll
    for (int r = 0; r < 4; ++r) {
      float mx = fmaxf(fmaxf(S[tm][0][r], S[tm][1][r]),
                       fmaxf(S[tm][2][r], S[tm][3][r]));
#pragma unroll
      for (int off = 1; off < 16; off <<= 1) mx = fmaxf(mx, __shfl_xor(mx, off));
      float sm = 0.f;
#pragma unroll
      for (int tn = 0; tn < 4; ++tn) {
        const float e = __expf(S[tm][tn][r] - mx);
        S[tm][tn][r] = e;
        sm += e;
      }
#pragma unroll
      for (int off = 1; off < 16; off <<= 1) sm += __shfl_xor(sm, off);
      const float inv = 1.0f / sm;
      const int n = tm * 16 + quad * 4 + r;
#pragma unroll
      for (int tn = 0; tn < 4; ++tn)
        sP[n * 72 + tn * 16 + l15] = f2bf(S[tm][tn][r] * inv);
    }
  __syncthreads();

  short8 vf[2][2];
#pragma unroll
  for (int ks = 0; ks < 2; ++ks)
#pragma unroll
    for (int td = 0; td < 2; ++td)
      vf[ks][td] =
          *(const short8*)&sVt[(td * 16 + l15) * 72 + ks * 32 + quad * 8];
  f32x4 O[4][2];
#pragma unroll
  for (int tm = 0; tm < 4; ++tm)
#pragma unroll
    for (int td = 0; td < 2; ++td) O[tm][td] = (f32x4){0.f, 0.f, 0.f, 0.f};
#pragma unroll
  for (int tm = 0; tm < 4; ++tm)
#pragma unroll
    for (int ks = 0; ks < 2; ++ks) {
      const short8 pf =
          *(const short8*)&sP[(tm * 16 + l15) * 72 + ks * 32 + quad * 8];
#pragma unroll
      for (int td = 0; td < 2; ++td)
        O[tm][td] =
            __builtin_amdgcn_mfma_f32_16x16x32_bf16(pf, vf[ks][td], O[tm][td], 0, 0, 0);
    }

#pragma unroll
  for (int tm = 0; tm < 4; ++tm)
#pragma unroll
    for (int td = 0; td < 2; ++td)
#pragma unroll
      for (int r = 0; r < 4; ++r) {
        const int n = tm * 16 + quad * 4 + r;
        const int d = td * 16 + l15;
        outp[(size_t)(w * 64 + n) * 512 + h * 32 + d] = f2bf(O[tm][td][r]);
      }
}

// ---------------------------------------------------------------------------
// Host
// ---------------------------------------------------------------------------
extern "C" void kernel_launch(void* const* d_in, const int* in_sizes, int n_in,
                              void* d_out, int out_size, void* d_ws,
                              size_t ws_size, hipStream_t stream) {
  const float* x = (const float*)d_in[0];
  const float* D = (const float*)d_in[1];
  const float* gamma1 = (const float*)d_in[2];
  const float* beta1 = (const float*)d_in[3];
  const float* Wqkv = (const float*)d_in[4];
  const float* bqkv = (const float*)d_in[5];
  const float* Wproj = (const float*)d_in[6];
  const float* bproj = (const float*)d_in[7];
  const float* a_p = (const float*)d_in[8];
  const float* b_p = (const float*)d_in[9];
  const float* a_r = (const float*)d_in[10];
  const float* b_r = (const float*)d_in[11];
  const float* gamma2 = (const float*)d_in[12];
  const float* beta2 = (const float*)d_in[13];
  const float* W1 = (const float*)d_in[14];
  const float* b1 = (const float*)d_in[15];
  const float* W2 = (const float*)d_in[16];
  const float* b2 = (const float*)d_in[17];
  float* out = (float*)d_out;

  char* ws = (char*)d_ws;
  const size_t OFF_XW = 0;                    // 67,108,864   (xw, later h2)
  const size_t OFF_QKV = 67108864;            // 268,435,456  (qkv, later g)
  const size_t OFF_AO = 335544320;            // 67,108,864   (attn out)
  const size_t OFF_WQT = 402653184;           // 1,572,864
  const size_t OFF_WPT = 404226048;           // 524,288
  const size_t OFF_W1T = 404750336;           // 2,097,152
  const size_t OFF_W2T = 406847488;           // 2,097,152
  const size_t OFF_APHI = 408944640;          // 262,144
  const size_t OFF_DW = 409206784;            // 262,144
  const size_t TOTAL = 409468928;
  if (ws_size < TOTAL) return;

  u16* xw = (u16*)(ws + OFF_XW);
  u16* qkv = (u16*)(ws + OFF_QKV);
  u16* ao = (u16*)(ws + OFF_AO);
  u16* WqkvT = (u16*)(ws + OFF_WQT);
  u16* WprojT = (u16*)(ws + OFF_WPT);
  u16* W1T = (u16*)(ws + OFF_W1T);
  u16* W2T = (u16*)(ws + OFF_W2T);
  float* aphiW = (float*)(ws + OFF_APHI);
  float* dwW = (float*)(ws + OFF_DW);
  u16* h2 = xw;   // reuse
  u16* gbuf = qkv;  // reuse

  wt_convert<<<dim3(48, 16), 256, 0, stream>>>(Wqkv, WqkvT, 512, 1536);
  wt_convert<<<dim3(16, 16), 256, 0, stream>>>(Wproj, WprojT, 512, 512);
  wt_convert<<<dim3(64, 16), 256, 0, stream>>>(W1, W1T, 512, 2048);
  wt_convert<<<dim3(16, 64), 256, 0, stream>>>(W2, W2T, 2048, 512);
  aphi_kernel<<<256, 256, 0, stream>>>(a_p, b_p, aphiW);
  ln1_win<<<65536, 64, 0, stream>>>(x, D, gamma1, beta1, xw, dwW);

  // 256x256 tiles: grid = (N/256) * 256 M-tiles
  gemm_bt<0, 6><<<6 * 256, 512, 0, stream>>>(xw, WqkvT, bqkv, qkv, nullptr,
                                             nullptr, 65536, 1536, 512);
  attn_kernel<<<16384, 64, 0, stream>>>(qkv, dwW, aphiW, a_r, b_r, ao);
  gemm_bt<2, 2><<<2 * 256, 512, 0, stream>>>(ao, WprojT, bproj, nullptr, out,
                                             x, 65536, 512, 512);
  ln2_kernel<<<65536, 64, 0, stream>>>(out, gamma2, beta2, h2);
  gemm_bt<1, 8><<<8 * 256, 512, 0, stream>>>(h2, W1T, b1, gbuf, nullptr,
                                             nullptr, 65536, 2048, 512);
  gemm_bt<3, 2><<<2 * 256, 512, 0, stream>>>(gbuf, W2T, b2, nullptr, out,
                                             nullptr, 65536, 512, 2048);
}

// Round 4
// 1084.863 us; speedup vs baseline: 1.1974x; 1.1568x over previous
//
#include <hip/hip_runtime.h>
#include <hip/hip_bf16.h>
#include <cstdint>

// Problem constants
// B=16, H=W=64, C=512, NH=16, WS=8, SS=4, P=4, HID=2048, N=64, HD=32
// Bw = 1024 windows, tokens = 65536

typedef __attribute__((ext_vector_type(8))) short short8;
typedef __attribute__((ext_vector_type(4))) float f32x4;
typedef unsigned short u16;

__device__ __forceinline__ u16 f2bf(float f) {
  __hip_bfloat16 h = __float2bfloat16(f);
  return *reinterpret_cast<u16*>(&h);
}

// ---------------------------------------------------------------------------
// Weight convert + transpose: W [K,N] fp32 -> Wt [N,K] bf16
// ---------------------------------------------------------------------------
__global__ void wt_convert(const float* __restrict__ W, u16* __restrict__ Wt,
                           int K, int N) {
  __shared__ float tile[32][33];
  const int n0 = blockIdx.x * 32, k0 = blockIdx.y * 32;
  const int tx = threadIdx.x & 31, ty = threadIdx.x >> 5;  // 32 x 8
#pragma unroll
  for (int r = ty; r < 32; r += 8)
    tile[r][tx] = W[(size_t)(k0 + r) * N + n0 + tx];
  __syncthreads();
#pragma unroll
  for (int r = ty; r < 32; r += 8)
    Wt[(size_t)(n0 + r) * K + k0 + tx] = f2bf(tile[tx][r]);
}

// ---------------------------------------------------------------------------
// A_phi precompute: [NH=16][n=64][m=64] fp32
// ---------------------------------------------------------------------------
__global__ void aphi_kernel(const float* __restrict__ a_p,
                            const float* __restrict__ b_p,
                            float* __restrict__ aphi) {
  const int idx = blockIdx.x * 256 + threadIdx.x;  // 65536 total
  const int h = idx >> 12, n = (idx >> 6) & 63, m = idx & 63;
  const float ang = (float)((n & 7) - (m & 7)) * 0.09817477042468103f;  // 2pi/64
  float v = a_p[h];
#pragma unroll
  for (int p = 0; p < 4; ++p) {
    float s, c;
    __sincosf((float)(p + 1) * ang, &s, &c);
    v += (c * a_p[(p + 1) * 16 + h] + s * b_p[p * 16 + h]) * 0.25f;
  }
  aphi[idx] = v;
}

// ---------------------------------------------------------------------------
// LN1 + roll(-4,-4) + window partition -> xw bf16 [65536,512], dw fp32 [65536]
// one wave per output row
// ---------------------------------------------------------------------------
__global__ __launch_bounds__(64) void ln1_win(
    const float* __restrict__ x, const float* __restrict__ D,
    const float* __restrict__ gamma, const float* __restrict__ beta,
    u16* __restrict__ xw, float* __restrict__ dwout) {
  const int r = blockIdx.x;
  const int lane = threadIdx.x;
  const int w = r >> 6, n = r & 63;
  const int bb = w >> 6, nw = w & 63;
  const int wh = nw >> 3, ww = nw & 7;
  const int i = n >> 3, j = n & 7;
  const int sh = (wh * 8 + i + 4) & 63;
  const int sw = (ww * 8 + j + 4) & 63;
  const size_t src = ((size_t)bb * 4096 + sh * 64 + sw) * 512;
  float4 v0 = *(const float4*)(x + src + lane * 8);
  float4 v1 = *(const float4*)(x + src + lane * 8 + 4);
  float vv[8] = {v0.x, v0.y, v0.z, v0.w, v1.x, v1.y, v1.z, v1.w};
  float s = 0.f, s2 = 0.f;
#pragma unroll
  for (int e = 0; e < 8; ++e) { s += vv[e]; s2 += vv[e] * vv[e]; }
#pragma unroll
  for (int off = 32; off > 0; off >>= 1) {
    s += __shfl_xor(s, off);
    s2 += __shfl_xor(s2, off);
  }
  const float mean = s * (1.0f / 512.0f);
  const float var = s2 * (1.0f / 512.0f) - mean * mean;
  const float rstd = rsqrtf(var + 1e-5f);
  const int c0 = lane * 8;
  u16 ob[8];
#pragma unroll
  for (int e = 0; e < 8; ++e)
    ob[e] = f2bf((vv[e] - mean) * rstd * gamma[c0 + e] + beta[c0 + e]);
  *(short8*)(xw + (size_t)r * 512 + c0) = *(short8*)ob;
  if (lane == 0) dwout[r] = D[(size_t)bb * 4096 + sh * 64 + sw];
}

// ---------------------------------------------------------------------------
// LN2 (token order): x2 fp32 -> h2 bf16
// ---------------------------------------------------------------------------
__global__ __launch_bounds__(64) void ln2_kernel(
    const float* __restrict__ xin, const float* __restrict__ gamma,
    const float* __restrict__ beta, u16* __restrict__ h2) {
  const int r = blockIdx.x;
  const int lane = threadIdx.x;
  const size_t src = (size_t)r * 512;
  float4 v0 = *(const float4*)(xin + src + lane * 8);
  float4 v1 = *(const float4*)(xin + src + lane * 8 + 4);
  float vv[8] = {v0.x, v0.y, v0.z, v0.w, v1.x, v1.y, v1.z, v1.w};
  float s = 0.f, s2 = 0.f;
#pragma unroll
  for (int e = 0; e < 8; ++e) { s += vv[e]; s2 += vv[e] * vv[e]; }
#pragma unroll
  for (int off = 32; off > 0; off >>= 1) {
    s += __shfl_xor(s, off);
    s2 += __shfl_xor(s2, off);
  }
  const float mean = s * (1.0f / 512.0f);
  const float var = s2 * (1.0f / 512.0f) - mean * mean;
  const float rstd = rsqrtf(var + 1e-5f);
  const int c0 = lane * 8;
  u16 ob[8];
#pragma unroll
  for (int e = 0; e < 8; ++e)
    ob[e] = f2bf((vv[e] - mean) * rstd * gamma[c0 + e] + beta[c0 + e]);
  *(short8*)(h2 + src + c0) = *(short8*)ob;
}

// ---------------------------------------------------------------------------
// bf16 GEMM, C[M,N] = A[M,K] * Bt[N,K]^T (+bias, +epilogue)
// 256x256 tile, BK=64, 512 threads = 8 waves (2M x 4N), 16x16x32 mfma.
// R4: REGISTER staging (global->VGPR->ds_write), T14 style. The compiler's
// waitcnt scoreboard is register-precise for plain loads, so it emits COUNTED
// vmcnt automatically (R1-R3 showed global_load_lds DMA gets conservative
// vmcnt(0) before any ds_read -> full-latency stall every phase).
// Pipeline, ONE __syncthreads per K-tile, double-buffered LDS:
//   ds_write regs(tile kt)          (auto-waits only tile-kt's loads)
//   __syncthreads                   (vmcnt already drained -> free)
//   issue 8x global_load tile kt+1  (hidden under the MFMA section)
//   ds_read frags + 64 MFMA
// Buf reuse hazard W(buf)@kt+2 vs R(buf)@kt is fenced by the barrier@kt+1.
// LDS XOR swizzle chunk^((row>>1)&3) on 64B khalf-rows, applied at ds_write
// and ds_read (reads verified conflict-free: SQ_LDS_BANK_CONFLICT=0).
// 1D grid + XCD swizzle: lid&7 stripes M across XCDs for A-panel L2 locality.
// EPI: 0 = bias->bf16; 1 = bias+gelu->bf16;
//      2 = bias + unwindow/unroll + residual(x) -> fp32 d_out;
//      3 = bias + accumulate into fp32 d_out (token order)
// ---------------------------------------------------------------------------
#define MFMA_BF16 __builtin_amdgcn_mfma_f32_16x16x32_bf16

template <int EPI, int GX>
__global__ __launch_bounds__(512, 2) void gemm_bt(
    const u16* __restrict__ A, const u16* __restrict__ Bt,
    const float* __restrict__ bias, u16* __restrict__ outb,
    float* __restrict__ outf, const float* __restrict__ addsrc,
    int M, int N, int K) {
  // layout: [buf(2)][khalf(2)][row(256)][physchunk(4) x 8 u16]
  __shared__ __align__(16) u16 sA[32768];
  __shared__ __align__(16) u16 sB[32768];
  const int t = threadIdx.x;
  const int lid = blockIdx.x;
  const int xcd = lid & 7;
  const int tt = lid >> 3;
  const int bx = tt % GX;
  const int by = (tt / GX) * 8 + xcd;
  const int m0 = by * 256, n0 = bx * 256;
  const int lane = t & 63, wave = t >> 6;
  const int wm = wave >> 2, wn = wave & 3;  // 2 x 4 wave grid
  const int l15 = lane & 15, quad = lane >> 4;

  f32x4 acc[8][4];
#pragma unroll
  for (int i = 0; i < 8; ++i)
#pragma unroll
    for (int j = 0; j < 4; ++j) acc[i][j] = (f32x4){0.f, 0.f, 0.f, 0.f};

  // staging: thread t covers rows r0 = t>>2 and r0+128, chunk c0 = t&3 (16B)
  // within each 64B khalf-row; ds_write to physchunk = c0 ^ ((row>>1)&3).
  const int r0 = t >> 2, c0 = t & 3;
  const int wo0 = r0 * 32 + ((c0 ^ ((r0 >> 1) & 3)) * 8);
  const int wo1 = (r0 + 128) * 32 + ((c0 ^ (((r0 + 128) >> 1) & 3)) * 8);
  const u16* Ag0 = A + (size_t)(m0 + r0) * K + c0 * 8;
  const u16* Ag1 = A + (size_t)(m0 + r0 + 128) * K + c0 * 8;
  const u16* Bg0 = Bt + (size_t)(n0 + r0) * K + c0 * 8;
  const u16* Bg1 = Bt + (size_t)(n0 + r0 + 128) * K + c0 * 8;

  const int NT = K >> 6;  // K-tiles of 64

  // read-side (u16 offsets): row*32 + physchunk*8, physchunk = quad^swz(row)
  const int pch8 = (quad ^ ((l15 >> 1) & 3)) * 8;
  const int aro = (wm * 128 + l15) * 32 + pch8;  // + i*512 (+8192 for khalf1)
  const int bro = (wn * 64 + l15) * 32 + pch8;   // + j*512

  // prologue: tile 0 -> regs (named regs: all indexing compile-time)
  short8 rA0 = *(const short8*)(Ag0);
  short8 rA1 = *(const short8*)(Ag1);
  short8 rA2 = *(const short8*)(Ag0 + 32);
  short8 rA3 = *(const short8*)(Ag1 + 32);
  short8 rB0 = *(const short8*)(Bg0);
  short8 rB1 = *(const short8*)(Bg1);
  short8 rB2 = *(const short8*)(Bg0 + 32);
  short8 rB3 = *(const short8*)(Bg1 + 32);

  for (int kt = 0; kt < NT; ++kt) {
    const int bo = (kt & 1) << 14;  // buffer offset (16384 u16)
    // W: commit tile kt to LDS
    *(short8*)&sA[bo + wo0] = rA0;
    *(short8*)&sA[bo + wo1] = rA1;
    *(short8*)&sA[bo + 8192 + wo0] = rA2;
    *(short8*)&sA[bo + 8192 + wo1] = rA3;
    *(short8*)&sB[bo + wo0] = rB0;
    *(short8*)&sB[bo + wo1] = rB1;
    *(short8*)&sB[bo + 8192 + wo0] = rB2;
    *(short8*)&sB[bo + 8192 + wo1] = rB3;
    __syncthreads();
    // prefetch tile kt+1 into regs (latency hidden under MFMA section)
    if (kt + 1 < NT) {
      const int ko = (kt + 1) * 64;
      rA0 = *(const short8*)(Ag0 + ko);
      rA1 = *(const short8*)(Ag1 + ko);
      rA2 = *(const short8*)(Ag0 + ko + 32);
      rA3 = *(const short8*)(Ag1 + ko + 32);
      rB0 = *(const short8*)(Bg0 + ko);
      rB1 = *(const short8*)(Bg1 + ko);
      rB2 = *(const short8*)(Bg0 + ko + 32);
      rB3 = *(const short8*)(Bg1 + ko + 32);
    }
    // R + MFMA over both k-halves
    const u16* bA = &sA[bo];
    const u16* bB = &sB[bo];
#pragma unroll
    for (int kh = 0; kh < 2; ++kh) {
      const int kho = kh * 8192;
      short8 a0[8];
#pragma unroll
      for (int i = 0; i < 8; ++i)
        a0[i] = *(const short8*)&bA[kho + aro + i * 512];
      const short8 b0 = *(const short8*)&bB[kho + bro];
      const short8 b1 = *(const short8*)&bB[kho + bro + 512];
      const short8 b2 = *(const short8*)&bB[kho + bro + 1024];
      const short8 b3 = *(const short8*)&bB[kho + bro + 1536];
#pragma unroll
      for (int i = 0; i < 8; ++i)
        acc[i][0] = MFMA_BF16(a0[i], b0, acc[i][0], 0, 0, 0);
#pragma unroll
      for (int i = 0; i < 8; ++i)
        acc[i][1] = MFMA_BF16(a0[i], b1, acc[i][1], 0, 0, 0);
#pragma unroll
      for (int i = 0; i < 8; ++i)
        acc[i][2] = MFMA_BF16(a0[i], b2, acc[i][2], 0, 0, 0);
#pragma unroll
      for (int i = 0; i < 8; ++i)
        acc[i][3] = MFMA_BF16(a0[i], b3, acc[i][3], 0, 0, 0);
    }
  }

#pragma unroll
  for (int i = 0; i < 8; ++i) {
    const int gr0 = m0 + wm * 128 + i * 16 + quad * 4;
#pragma unroll
    for (int j = 0; j < 4; ++j) {
      const int gc = n0 + wn * 64 + j * 16 + l15;
      const float bv = bias[gc];
      f32x4 a = acc[i][j];
#pragma unroll
      for (int r = 0; r < 4; ++r) {
        const int gr = gr0 + r;
        float val = a[r] + bv;
        if (EPI == 0) {
          outb[(size_t)gr * N + gc] = f2bf(val);
        } else if (EPI == 1) {
          val = 0.5f * val * (1.0f + erff(val * 0.7071067811865475f));
          outb[(size_t)gr * N + gc] = f2bf(val);
        } else if (EPI == 2) {
          const int w = gr >> 6, n = gr & 63;
          const int bb = w >> 6, nw = w & 63;
          const int wh = nw >> 3, ww = nw & 7;
          const int ii = n >> 3, jj = n & 7;
          const int th = (wh * 8 + ii + 4) & 63;
          const int tw = (ww * 8 + jj + 4) & 63;
          const size_t tok = (size_t)bb * 4096 + th * 64 + tw;
          outf[tok * 512 + gc] = addsrc[tok * 512 + gc] + val;
        } else {
          outf[(size_t)gr * N + gc] += val;
        }
      }
    }
  }
}

// ---------------------------------------------------------------------------
// Fused windowed attention, one wave per (window, head).
// S = QK^T*scale + A_phi + A_r(trig recurrence) + shift-mask; in-register
// softmax (16-lane shuffles); P -> LDS -> A-frag; O = P V via mfma.
// ---------------------------------------------------------------------------
__device__ __forceinline__ int bandf(int p) {
  return p < 56 ? 0 : (p < 60 ? 1 : 2);
}

__global__ void attn_kernel(const u16* __restrict__ qkv,
                            const float* __restrict__ dw,
                            const float* __restrict__ aphi,
                            const float* __restrict__ a_r,
                            const float* __restrict__ b_r,
                            u16* __restrict__ outp) {
  __shared__ __align__(16) u16 sVt[32 * 72];
  __shared__ __align__(16) u16 sP[64 * 72];
  __shared__ float sdw[64];
  const int bid = blockIdx.x;
  const int w = bid >> 4, h = bid & 15;
  const int lane = threadIdx.x;
  const int l15 = lane & 15, quad = lane >> 4;
  const int nw = w & 63, wh = nw >> 3, wwc = nw & 7;

  const float ar0 = a_r[h];
  float arc[4], brc[4];
#pragma unroll
  for (int p = 0; p < 4; ++p) {
    arc[p] = a_r[(p + 1) * 16 + h] * 0.25f;
    brc[p] = b_r[p * 16 + h] * 0.25f;
  }

  sdw[lane] = dw[w * 64 + lane];
  {
    const u16* vrow = qkv + (size_t)(w * 64 + lane) * 1536 + 1024 + h * 32;
    u16 vt[32];
#pragma unroll
    for (int c = 0; c < 4; ++c)
      *(short8*)&vt[c * 8] = *(const short8*)(vrow + c * 8);
#pragma unroll
    for (int d = 0; d < 32; ++d) sVt[d * 72 + lane] = vt[d];
  }
  __syncthreads();

  short8 qf[4], kf[4];
#pragma unroll
  for (int tq = 0; tq < 4; ++tq) {
    qf[tq] = *(const short8*)(qkv + (size_t)(w * 64 + tq * 16 + l15) * 1536 +
                              h * 32 + quad * 8);
    kf[tq] = *(const short8*)(qkv + (size_t)(w * 64 + tq * 16 + l15) * 1536 +
                              512 + h * 32 + quad * 8);
  }

  float dn[16];
  int rq[16];
#pragma unroll
  for (int tm = 0; tm < 4; ++tm)
#pragma unroll
    for (int r = 0; r < 4; ++r) {
      const int n = tm * 16 + quad * 4 + r;
      dn[tm * 4 + r] = sdw[n];
      rq[tm * 4 + r] = bandf(wh * 8 + (n >> 3)) * 4 + bandf(wwc * 8 + (n & 7));
    }
  float dmv[4];
  int rk[4];
#pragma unroll
  for (int tn = 0; tn < 4; ++tn) {
    const int m = tn * 16 + l15;
    dmv[tn] = sdw[m];
    rk[tn] = bandf(wh * 8 + (m >> 3)) * 4 + bandf(wwc * 8 + (m & 7));
  }

  f32x4 S[4][4];
  const float SCALE = 0.17677669529663687f;  // 32^-0.5
#pragma unroll
  for (int tm = 0; tm < 4; ++tm)
#pragma unroll
    for (int tn = 0; tn < 4; ++tn) {
      f32x4 s = __builtin_amdgcn_mfma_f32_16x16x32_bf16(
          qf[tm], kf[tn], (f32x4){0.f, 0.f, 0.f, 0.f}, 0, 0, 0);
      const int m = tn * 16 + l15;
#pragma unroll
      for (int r = 0; r < 4; ++r) {
        const int n = tm * 16 + quad * 4 + r;
        const float rad = dmv[tn] - dn[tm * 4 + r];
        float s1, c1;
        __sincosf(3.14159265358979323846f * rad, &s1, &c1);
        const float c2 = c1 * c1 - s1 * s1, t2 = 2.f * s1 * c1;
        const float c3 = c2 * c1 - t2 * s1, t3 = t2 * c1 + c2 * s1;
        const float c4 = c2 * c2 - t2 * t2, t4 = 2.f * t2 * c2;
        const float arv = ar0 + c1 * arc[0] + s1 * brc[0] + c2 * arc[1] +
                          t2 * brc[1] + c3 * arc[2] + t3 * brc[2] +
                          c4 * arc[3] + t4 * brc[3];
        float val = s[r] * SCALE + aphi[h * 4096 + n * 64 + m] + arv;
        if (rq[tm * 4 + r] != rk[tn]) val -= 100.f;
        S[tm][tn][r] = val;
      }
    }

#pragma unroll
  for (int tm = 0; tm < 4; ++tm)
#pragma unroll
    for (int r = 0; r < 4; ++r) {
      float mx = fmaxf(fmaxf(S[tm][0][r], S[tm][1][r]),
                       fmaxf(S[tm][2][r], S[tm][3][r]));
#pragma unroll
      for (int off = 1; off < 16; off <<= 1) mx = fmaxf(mx, __shfl_xor(mx, off));
      float sm = 0.f;
#pragma unroll
      for (int tn = 0; tn < 4; ++tn) {
        const float e = __expf(S[tm][tn][r] - mx);
        S[tm][tn][r] = e;
        sm += e;
      }
#pragma unroll
      for (int off = 1; off < 16; off <<= 1) sm += __shfl_xor(sm, off);
      const float inv = 1.0f / sm;
      const int n = tm * 16 + quad * 4 + r;
#pragma unroll
      for (int tn = 0; tn < 4; ++tn)
        sP[n * 72 + tn * 16 + l15] = f2bf(S[tm][tn][r] * inv);
    }
  __syncthreads();

  short8 vf[2][2];
#pragma unroll
  for (int ks = 0; ks < 2; ++ks)
#pragma unroll
    for (int td = 0; td < 2; ++td)
      vf[ks][td] =
          *(const short8*)&sVt[(td * 16 + l15) * 72 + ks * 32 + quad * 8];
  f32x4 O[4][2];
#pragma unroll
  for (int tm = 0; tm < 4; ++tm)
#pragma unroll
    for (int td = 0; td < 2; ++td) O[tm][td] = (f32x4){0.f, 0.f, 0.f, 0.f};
#pragma unroll
  for (int tm = 0; tm < 4; ++tm)
#pragma unroll
    for (int ks = 0; ks < 2; ++ks) {
      const short8 pf =
          *(const short8*)&sP[(tm * 16 + l15) * 72 + ks * 32 + quad * 8];
#pragma unroll
      for (int td = 0; td < 2; ++td)
        O[tm][td] =
            __builtin_amdgcn_mfma_f32_16x16x32_bf16(pf, vf[ks][td], O[tm][td], 0, 0, 0);
    }

#pragma unroll
  for (int tm = 0; tm < 4; ++tm)
#pragma unroll
    for (int td = 0; td < 2; ++td)
#pragma unroll
      for (int r = 0; r < 4; ++r) {
        const int n = tm * 16 + quad * 4 + r;
        const int d = td * 16 + l15;
        outp[(size_t)(w * 64 + n) * 512 + h * 32 + d] = f2bf(O[tm][td][r]);
      }
}

// ---------------------------------------------------------------------------
// Host
// ---------------------------------------------------------------------------
extern "C" void kernel_launch(void* const* d_in, const int* in_sizes, int n_in,
                              void* d_out, int out_size, void* d_ws,
                              size_t ws_size, hipStream_t stream) {
  const float* x = (const float*)d_in[0];
  const float* D = (const float*)d_in[1];
  const float* gamma1 = (const float*)d_in[2];
  const float* beta1 = (const float*)d_in[3];
  const float* Wqkv = (const float*)d_in[4];
  const float* bqkv = (const float*)d_in[5];
  const float* Wproj = (const float*)d_in[6];
  const float* bproj = (const float*)d_in[7];
  const float* a_p = (const float*)d_in[8];
  const float* b_p = (const float*)d_in[9];
  const float* a_r = (const float*)d_in[10];
  const float* b_r = (const float*)d_in[11];
  const float* gamma2 = (const float*)d_in[12];
  const float* beta2 = (const float*)d_in[13];
  const float* W1 = (const float*)d_in[14];
  const float* b1 = (const float*)d_in[15];
  const float* W2 = (const float*)d_in[16];
  const float* b2 = (const float*)d_in[17];
  float* out = (float*)d_out;

  char* ws = (char*)d_ws;
  const size_t OFF_XW = 0;                    // 67,108,864   (xw, later h2)
  const size_t OFF_QKV = 67108864;            // 268,435,456  (qkv, later g)
  const size_t OFF_AO = 335544320;            // 67,108,864   (attn out)
  const size_t OFF_WQT = 402653184;           // 1,572,864
  const size_t OFF_WPT = 404226048;           // 524,288
  const size_t OFF_W1T = 404750336;           // 2,097,152
  const size_t OFF_W2T = 406847488;           // 2,097,152
  const size_t OFF_APHI = 408944640;          // 262,144
  const size_t OFF_DW = 409206784;            // 262,144
  const size_t TOTAL = 409468928;
  if (ws_size < TOTAL) return;

  u16* xw = (u16*)(ws + OFF_XW);
  u16* qkv = (u16*)(ws + OFF_QKV);
  u16* ao = (u16*)(ws + OFF_AO);
  u16* WqkvT = (u16*)(ws + OFF_WQT);
  u16* WprojT = (u16*)(ws + OFF_WPT);
  u16* W1T = (u16*)(ws + OFF_W1T);
  u16* W2T = (u16*)(ws + OFF_W2T);
  float* aphiW = (float*)(ws + OFF_APHI);
  float* dwW = (float*)(ws + OFF_DW);
  u16* h2 = xw;   // reuse
  u16* gbuf = qkv;  // reuse

  wt_convert<<<dim3(48, 16), 256, 0, stream>>>(Wqkv, WqkvT, 512, 1536);
  wt_convert<<<dim3(16, 16), 256, 0, stream>>>(Wproj, WprojT, 512, 512);
  wt_convert<<<dim3(64, 16), 256, 0, stream>>>(W1, W1T, 512, 2048);
  wt_convert<<<dim3(16, 64), 256, 0, stream>>>(W2, W2T, 2048, 512);
  aphi_kernel<<<256, 256, 0, stream>>>(a_p, b_p, aphiW);
  ln1_win<<<65536, 64, 0, stream>>>(x, D, gamma1, beta1, xw, dwW);

  // 256x256 tiles: grid = (N/256) * 256 M-tiles
  gemm_bt<0, 6><<<6 * 256, 512, 0, stream>>>(xw, WqkvT, bqkv, qkv, nullptr,
                                             nullptr, 65536, 1536, 512);
  attn_kernel<<<16384, 64, 0, stream>>>(qkv, dwW, aphiW, a_r, b_r, ao);
  gemm_bt<2, 2><<<2 * 256, 512, 0, stream>>>(ao, WprojT, bproj, nullptr, out,
                                             x, 65536, 512, 512);
  ln2_kernel<<<65536, 64, 0, stream>>>(out, gamma2, beta2, h2);
  gemm_bt<1, 8><<<8 * 256, 512, 0, stream>>>(h2, W1T, b1, gbuf, nullptr,
                                             nullptr, 65536, 2048, 512);
  gemm_bt<3, 2><<<2 * 256, 512, 0, stream>>>(gbuf, W2T, b2, nullptr, out,
                                             nullptr, 65536, 512, 2048);
}